// Round 3
// baseline (2209.880 us; speedup 1.0000x reference)
//
#include <hip/hip_runtime.h>
#include <cstdint>

typedef float  f32x4  __attribute__((ext_vector_type(4)));
typedef __bf16 bf16x8 __attribute__((ext_vector_type(8)));
typedef int    i32x4  __attribute__((ext_vector_type(4)));
typedef unsigned short u16;
typedef u16 u16x4 __attribute__((ext_vector_type(4)));

#define TT 512

// ---------- helpers ----------
__device__ __forceinline__ u16 f2bf(float f) {
  unsigned u = __builtin_bit_cast(unsigned, f);
  unsigned r = u + 0x7fffu + ((u >> 16) & 1u);   // RNE
  return (u16)(r >> 16);
}
__device__ __forceinline__ float bflo(unsigned d) { return __builtin_bit_cast(float, d << 16); }
__device__ __forceinline__ float bfhi(unsigned d) { return __builtin_bit_cast(float, d & 0xffff0000u); }
__device__ __forceinline__ float rcpf(float x) { return __builtin_amdgcn_rcpf(x); }
__device__ __forceinline__ float fsig(float x) { return rcpf(1.f + __expf(-x)); }
__device__ __forceinline__ float ftanh(float x) { return 1.f - 2.f * rcpf(1.f + __expf(2.f * x)); }
__device__ __forceinline__ void gload_lds16(const u16* g, u16* l) {
  __builtin_amdgcn_global_load_lds((const __attribute__((address_space(1))) void*)(g),
                                   (__attribute__((address_space(3))) void*)(l), 16, 0, 0);
}

// ---------- prep: x (N,T,D) fp32 -> xb (T,N,D) bf16, 4 elems/thread ----------
__global__ __launch_bounds__(256) void prep_x(const float* __restrict__ x, u16* __restrict__ xb) {
  long o = ((long)blockIdx.x * 256 + threadIdx.x) * 4;   // 33,554,432 total elems
  int d = (int)(o & 255);
  int n = (int)((o >> 8) & 255);
  int t = (int)(o >> 16);
  const float4 v = *(const float4*)(x + ((long)n << 17) + ((long)t << 8) + d);
  u16x4 p;
  p[0] = f2bf(v.x); p[1] = f2bf(v.y); p[2] = f2bf(v.z); p[3] = f2bf(v.w);
  *(u16x4*)(xb + o) = p;
}

// ---------- prep: Wx -> bf16 transposed; Wh -> i8 per-col quant; bias sum ----------
__global__ __launch_bounds__(256) void prep_w(
    const float* __restrict__ wii, const float* __restrict__ whi,
    const float* __restrict__ wif, const float* __restrict__ whf,
    const float* __restrict__ wig, const float* __restrict__ whg,
    const float* __restrict__ wio, const float* __restrict__ who,
    const float* __restrict__ bii, const float* __restrict__ bhi,
    const float* __restrict__ bif, const float* __restrict__ bhf,
    const float* __restrict__ big_, const float* __restrict__ bhg,
    const float* __restrict__ bio, const float* __restrict__ bho,
    u16* __restrict__ Wxb, signed char* __restrict__ Whq,
    float* __restrict__ wscale, float* __restrict__ bsum) {
  __shared__ float red[256];
  int b = blockIdx.x;
  int tid = threadIdx.x;
  if (b < 1024) {                 // Wxb_t[col][d] = w_x{G}[d][h], col = G*256+h
    const float* wx[4] = {wii, wif, wig, wio};
    int G = b >> 8, h = b & 255;
    Wxb[b * 256 + tid] = f2bf(wx[G][tid * 256 + h]);
  } else if (b < 2048) {          // Whq[col][u] = quant(w_h{G}[u][h]), per-col scale
    const float* wh[4] = {whi, whf, whg, who};
    int cidx = b - 1024;
    int G = cidx >> 8, h = cidx & 255;
    float w = wh[G][tid * 256 + h];
    red[tid] = fabsf(w);
    __syncthreads();
    for (int s = 128; s > 0; s >>= 1) {
      if (tid < s) red[tid] = fmaxf(red[tid], red[tid + s]);
      __syncthreads();
    }
    float mx = red[0];
    float scale = (mx > 0.f) ? mx * (1.f / 127.f) : 1.f;
    float qf = rintf(w / scale);
    qf = fminf(127.f, fmaxf(-127.f, qf));
    Whq[cidx * 256 + tid] = (signed char)(int)qf;
    if (tid == 0) wscale[cidx] = scale * (1.f / 127.f);   // combined w-scale * h-scale
  } else {
    const float* bx[4] = {bii, bif, big_, bio};
    const float* bh[4] = {bhi, bhf, bhg, bho};
    for (int G = 0; G < 4; ++G) bsum[G * 256 + tid] = bx[G][tid] + bh[G][tid];
  }
}

// ---------- phase 1: xWp = pack(xb @ Wx + b), m97-style 128x128 tile ----------
// Output tile-packed (MFMA C layout): xWp[(tm*64+tn)*256 + l*4 + r],
// lane l = q*16+c -> rows q*4+r, col c of tile (tm,tn).
__global__ __launch_bounds__(256) void gemm_xw(const u16* __restrict__ A, const u16* __restrict__ Bt,
                                               const float* __restrict__ bias, u16* __restrict__ xWp) {
  __shared__ u16 As[128 * 32];
  __shared__ u16 Bs[128 * 32];
  int bid = blockIdx.x;
  int bm = bid & 1023, bn = bid >> 10;
  int tid = threadIdx.x;
  int l = tid & 63, w = tid >> 6;
  int wm = w >> 1, wn = w & 1;
  f32x4 acc[4][4];
#pragma unroll
  for (int i = 0; i < 4; ++i)
#pragma unroll
    for (int j = 0; j < 4; ++j) acc[i][j] = (f32x4){0.f, 0.f, 0.f, 0.f};

  const u16* Ab = A + (size_t)bm * 128 * 256;
  const u16* Bb = Bt + (size_t)bn * 128 * 256;
  int row = tid >> 2;
  int ch = tid & 3;
  for (int ko = 0; ko < 8; ++ko) {
    __syncthreads();
    gload_lds16(Ab + (size_t)row * 256 + ko * 32 + ch * 8, As + tid * 8);
    gload_lds16(Ab + (size_t)(row + 64) * 256 + ko * 32 + ch * 8, As + 2048 + tid * 8);
    gload_lds16(Bb + (size_t)row * 256 + ko * 32 + ch * 8, Bs + tid * 8);
    gload_lds16(Bb + (size_t)(row + 64) * 256 + ko * 32 + ch * 8, Bs + 2048 + tid * 8);
    __syncthreads();
    bf16x8 af[4], bfr[4];
#pragma unroll
    for (int mt = 0; mt < 4; ++mt)
      af[mt] = *reinterpret_cast<const bf16x8*>(As + (wm * 64 + mt * 16 + (l & 15)) * 32 + (l >> 4) * 8);
#pragma unroll
    for (int nt = 0; nt < 4; ++nt)
      bfr[nt] = *reinterpret_cast<const bf16x8*>(Bs + (wn * 64 + nt * 16 + (l & 15)) * 32 + (l >> 4) * 8);
#pragma unroll
    for (int mt = 0; mt < 4; ++mt)
#pragma unroll
      for (int nt = 0; nt < 4; ++nt)
        acc[mt][nt] = __builtin_amdgcn_mfma_f32_16x16x32_bf16(af[mt], bfr[nt], acc[mt][nt], 0, 0, 0);
  }
#pragma unroll
  for (int mt = 0; mt < 4; ++mt) {
    int tm = bm * 8 + wm * 4 + mt;
#pragma unroll
    for (int nt = 0; nt < 4; ++nt) {
      int tn = bn * 8 + wn * 4 + nt;
      float bv = bias[tn * 16 + (l & 15)];
      u16x4 pk;
#pragma unroll
      for (int r = 0; r < 4; ++r) pk[r] = f2bf(acc[mt][nt][r] + bv);
      *reinterpret_cast<u16x4*>(xWp + ((size_t)(tm * 64 + tn) * 256 + l * 4)) = pk;
    }
  }
}

// ---------- phase 2: recurrence, fully CU-local ----------
// 64 wgs x 512 threads (8 waves, 2/SIMD). Swizzled so the 4 wgs sharing one
// xW step-tile sit on the same XCD. Each wg owns 4 batch rows; wave wid owns
// hidden units wid*32..+31 for all 4 gates (Wh i8 slice resident, 128 regs).
// h_t in LDS i8, double-buffered, row stride 288 B (2-way banks = free).
// Raw s_barrier + lgkm-only waitcnt; NO asm memory clobbers so the xW
// register prefetch stays in flight across the barrier (no vmcnt(0) drain).
__global__ __launch_bounds__(512, 2) void lstm_rec(const signed char* __restrict__ Whq,
                                                   const float* __restrict__ wscale,
                                                   const u16* __restrict__ xWp,
                                                   float* __restrict__ out) {
  __shared__ __align__(16) signed char hb[2][1152];   // 2 x (4 rows x 288B)
  int p = blockIdx.x;            // 0..63
  int G = (p & 7) * 2 + (p >> 5);      // chain-group 0..15 (co-XCD sharers)
  int q4 = (p >> 3) & 3;               // row-quad within the 16-row tile
  int tid = threadIdx.x;
  int wid = tid >> 6, l = tid & 63;
  int c = l & 15, q = (l >> 4) & 3;
  int tt = q >> 1, rsel = q & 1;

  for (int i = tid; i < 2 * 1152 / 4; i += 512) ((int*)hb)[i] = 0;

  // Wh i8 fragments: [gate][tt-tile][kstep], 16B each = 128 VGPRs/AGPRs
  i32x4 bw[4][2][4];
#pragma unroll
  for (int g = 0; g < 4; ++g)
#pragma unroll
    for (int ttl = 0; ttl < 2; ++ttl) {
      int col = g * 256 + wid * 32 + ttl * 16 + c;
#pragma unroll
      for (int ks = 0; ks < 4; ++ks)
        bw[g][ttl][ks] = *reinterpret_cast<const i32x4*>(Whq + (size_t)col * 256 + ks * 64 + q * 16);
    }
  float sc8[4];
#pragma unroll
  for (int g = 0; g < 4; ++g) sc8[g] = wscale[g * 256 + wid * 32 + tt * 16 + c];

  // xW addressing: byte base for step t = (t*16 + G)*32768
  const char* xbase = (const char*)xWp + (size_t)G * 32768;
  int xoff[4];
#pragma unroll
  for (int g = 0; g < 4; ++g) {
    int tn = g * 16 + wid * 2 + tt;
    xoff[g] = tn * 512 + (q4 * 16 + c) * 8 + rsel * 4;
  }
  unsigned xw[2][4];
#pragma unroll
  for (int g = 0; g < 4; ++g) xw[0][g] = *(const unsigned*)(xbase + xoff[g]);   // t=0
  xbase += 524288;   // -> t=1

  float cs[2] = {0.f, 0.f}, hh[2] = {0.f, 0.f};
  __syncthreads();

#pragma unroll 2
  for (int t = 0; t < TT; ++t) {
    int cur = t & 1, nxt = cur ^ 1;
    // prefetch xW for t+1 (stays in flight across the barrier)
#pragma unroll
    for (int g = 0; g < 4; ++g) xw[nxt][g] = *(const unsigned*)(xbase + xoff[g]);

    // h_{t-1} fragments (A rows replicated via (c&3)) + MFMA
    const signed char* hr = hb[nxt];
    i32x4 acc[4][2];
#pragma unroll
    for (int g = 0; g < 4; ++g)
#pragma unroll
      for (int ttl = 0; ttl < 2; ++ttl) acc[g][ttl] = (i32x4){0, 0, 0, 0};
#pragma unroll
    for (int ks = 0; ks < 4; ++ks) {
      i32x4 a = *reinterpret_cast<const i32x4*>(hr + (c & 3) * 288 + ks * 64 + q * 16);
#pragma unroll
      for (int g = 0; g < 4; ++g) {
        acc[g][0] = __builtin_amdgcn_mfma_i32_16x16x64_i8(a, bw[g][0][ks], acc[g][0], 0, 0, 0);
        acc[g][1] = __builtin_amdgcn_mfma_i32_16x16x64_i8(a, bw[g][1][ks], acc[g][1], 0, 0, 0);
      }
    }

    // elementwise: lane owns cells (rows 2*rsel+{0,1}, unit wid*32+tt*16+c)
    float a4[4][2];
#pragma unroll
    for (int g = 0; g < 4; ++g) {
      i32x4 av = tt ? acc[g][1] : acc[g][0];
      int e0 = rsel ? av[2] : av[0];
      int e1 = rsel ? av[3] : av[1];
      unsigned d = xw[cur][g];
      a4[g][0] = (float)e0 * sc8[g] + bflo(d);
      a4[g][1] = (float)e1 * sc8[g] + bfhi(d);
    }
    signed char* hw = hb[cur];
#pragma unroll
    for (int j = 0; j < 2; ++j) {
      float gi = fsig(a4[0][j]);
      float gf = fsig(a4[1][j]);
      float gg = ftanh(a4[2][j]);
      float go = fsig(a4[3][j]);
      float cc = gf * cs[j] + gi * gg;
      cs[j] = cc;
      float h = go * ftanh(cc);
      hh[j] = h;
      int hq = (int)rintf(h * 127.f);
      hw[(2 * rsel + j) * 288 + wid * 32 + tt * 16 + c] = (signed char)hq;
    }
    xbase += 524288;

    // raw barrier: wait LDS only (lgkmcnt(0)), leave vmcnt in flight.
    // No asm memory clobbers -> backend keeps exact vmcnt tracking.
    __builtin_amdgcn_s_waitcnt(0xC07F);
    __builtin_amdgcn_s_barrier();
  }

#pragma unroll
  for (int j = 0; j < 2; ++j) {
    int n = G * 16 + q4 * 4 + 2 * rsel + j;
    int hu = wid * 32 + tt * 16 + c;
    out[(size_t)n * 256 + hu] = hh[j];
    out[65536 + (size_t)n * 256 + hu] = cs[j];
  }
}

// ---------- launch ----------
extern "C" void kernel_launch(void* const* d_in, const int* in_sizes, int n_in,
                              void* d_out, int out_size, void* d_ws, size_t ws_size,
                              hipStream_t stream) {
  const float* x   = (const float*)d_in[0];
  const float* wii = (const float*)d_in[1];
  const float* whi = (const float*)d_in[2];
  const float* wif = (const float*)d_in[3];
  const float* whf = (const float*)d_in[4];
  const float* wig = (const float*)d_in[5];
  const float* whg = (const float*)d_in[6];
  const float* wio = (const float*)d_in[7];
  const float* who = (const float*)d_in[8];
  const float* bii = (const float*)d_in[9];
  const float* bhi = (const float*)d_in[10];
  const float* bif = (const float*)d_in[11];
  const float* bhf = (const float*)d_in[12];
  const float* big_ = (const float*)d_in[13];
  const float* bhg = (const float*)d_in[14];
  const float* bio = (const float*)d_in[15];
  const float* bho = (const float*)d_in[16];

  char* ws = (char*)d_ws;
  u16*   xb     = (u16*)(ws);                         // 67,108,864 B
  u16*   Wxb    = (u16*)(ws + 67108864);              //    524,288 B
  signed char* Whq = (signed char*)(ws + 67633152);   //    262,144 B
  float* wscale = (float*)(ws + 67895296);            //      4,096 B
  float* bsum   = (float*)(ws + 67899392);            //      4,096 B
  u16*   xWp    = (u16*)(ws + 67903488);              // 268,435,456 B + 524,288 B prefetch pad
  float* out = (float*)d_out;

  prep_x<<<32768, 256, 0, stream>>>(x, xb);
  prep_w<<<2049, 256, 0, stream>>>(wii, whi, wif, whf, wig, whg, wio, who,
                                   bii, bhi, bif, bhf, big_, bhg, bio, bho,
                                   Wxb, Whq, wscale, bsum);
  gemm_xw<<<8192, 256, 0, stream>>>(xb, Wxb, bsum, xWp);
  lstm_rec<<<64, 512, 0, stream>>>(Whq, wscale, xWp, out);
}

// Round 4
// 746.402 us; speedup vs baseline: 2.9607x; 2.9607x over previous
//
#include <hip/hip_runtime.h>
#include <cstdint>

typedef float  f32x4  __attribute__((ext_vector_type(4)));
typedef __bf16 bf16x8 __attribute__((ext_vector_type(8)));
typedef int    i32x4  __attribute__((ext_vector_type(4)));
typedef unsigned short u16;
typedef u16 u16x4 __attribute__((ext_vector_type(4)));

#define TT 512

// ---------- helpers ----------
__device__ __forceinline__ u16 f2bf(float f) {
  unsigned u = __builtin_bit_cast(unsigned, f);
  unsigned r = u + 0x7fffu + ((u >> 16) & 1u);   // RNE
  return (u16)(r >> 16);
}
__device__ __forceinline__ float bflo(unsigned d) { return __builtin_bit_cast(float, d << 16); }
__device__ __forceinline__ float bfhi(unsigned d) { return __builtin_bit_cast(float, d & 0xffff0000u); }
__device__ __forceinline__ float rcpf(float x) { return __builtin_amdgcn_rcpf(x); }
__device__ __forceinline__ float fsig(float x) { return rcpf(1.f + __expf(-x)); }
__device__ __forceinline__ float ftanh(float x) { return 1.f - 2.f * rcpf(1.f + __expf(2.f * x)); }
__device__ __forceinline__ void gload_lds16(const u16* g, u16* l) {
  __builtin_amdgcn_global_load_lds((const __attribute__((address_space(1))) void*)(g),
                                   (__attribute__((address_space(3))) void*)(l), 16, 0, 0);
}

// ---------- prep: x (N,T,D) fp32 -> xb (T,N,D) bf16, 4 elems/thread ----------
__global__ __launch_bounds__(256) void prep_x(const float* __restrict__ x, u16* __restrict__ xb) {
  long o = ((long)blockIdx.x * 256 + threadIdx.x) * 4;   // 33,554,432 total elems
  int d = (int)(o & 255);
  int n = (int)((o >> 8) & 255);
  int t = (int)(o >> 16);
  const float4 v = *(const float4*)(x + ((long)n << 17) + ((long)t << 8) + d);
  u16x4 p;
  p[0] = f2bf(v.x); p[1] = f2bf(v.y); p[2] = f2bf(v.z); p[3] = f2bf(v.w);
  *(u16x4*)(xb + o) = p;
}

// ---------- prep: Wx -> bf16 transposed; Wh -> i8 per-col quant; bias sum ----------
__global__ __launch_bounds__(256) void prep_w(
    const float* __restrict__ wii, const float* __restrict__ whi,
    const float* __restrict__ wif, const float* __restrict__ whf,
    const float* __restrict__ wig, const float* __restrict__ whg,
    const float* __restrict__ wio, const float* __restrict__ who,
    const float* __restrict__ bii, const float* __restrict__ bhi,
    const float* __restrict__ bif, const float* __restrict__ bhf,
    const float* __restrict__ big_, const float* __restrict__ bhg,
    const float* __restrict__ bio, const float* __restrict__ bho,
    u16* __restrict__ Wxb, signed char* __restrict__ Whq,
    float* __restrict__ wscale, float* __restrict__ bsum) {
  __shared__ float red[256];
  int b = blockIdx.x;
  int tid = threadIdx.x;
  if (b < 1024) {                 // Wxb_t[col][d] = w_x{G}[d][h], col = G*256+h
    const float* wx[4] = {wii, wif, wig, wio};
    int G = b >> 8, h = b & 255;
    Wxb[b * 256 + tid] = f2bf(wx[G][tid * 256 + h]);
  } else if (b < 2048) {          // Whq[col][u] = quant(w_h{G}[u][h]), per-col scale
    const float* wh[4] = {whi, whf, whg, who};
    int cidx = b - 1024;
    int G = cidx >> 8, h = cidx & 255;
    float w = wh[G][tid * 256 + h];
    red[tid] = fabsf(w);
    __syncthreads();
    for (int s = 128; s > 0; s >>= 1) {
      if (tid < s) red[tid] = fmaxf(red[tid], red[tid + s]);
      __syncthreads();
    }
    float mx = red[0];
    float scale = (mx > 0.f) ? mx * (1.f / 127.f) : 1.f;
    float qf = rintf(w / scale);
    qf = fminf(127.f, fmaxf(-127.f, qf));
    Whq[cidx * 256 + tid] = (signed char)(int)qf;
    if (tid == 0) wscale[cidx] = scale * (1.f / 127.f);   // combined w-scale * h-scale
  } else {
    const float* bx[4] = {bii, bif, big_, bio};
    const float* bh[4] = {bhi, bhf, bhg, bho};
    for (int G = 0; G < 4; ++G) bsum[G * 256 + tid] = bx[G][tid] + bh[G][tid];
  }
}

// ---------- phase 1: xWp = pack(xb @ Wx + b), m97-style 128x128 tile ----------
// Output tile-packed (MFMA C layout): xWp[(tm*64+tn)*256 + l*4 + r],
// lane l = q*16+c -> rows q*4+r, col c of tile (tm,tn).
__global__ __launch_bounds__(256) void gemm_xw(const u16* __restrict__ A, const u16* __restrict__ Bt,
                                               const float* __restrict__ bias, u16* __restrict__ xWp) {
  __shared__ u16 As[128 * 32];
  __shared__ u16 Bs[128 * 32];
  int bid = blockIdx.x;
  int bm = bid & 1023, bn = bid >> 10;
  int tid = threadIdx.x;
  int l = tid & 63, w = tid >> 6;
  int wm = w >> 1, wn = w & 1;
  f32x4 acc[4][4];
#pragma unroll
  for (int i = 0; i < 4; ++i)
#pragma unroll
    for (int j = 0; j < 4; ++j) acc[i][j] = (f32x4){0.f, 0.f, 0.f, 0.f};

  const u16* Ab = A + (size_t)bm * 128 * 256;
  const u16* Bb = Bt + (size_t)bn * 128 * 256;
  int row = tid >> 2;
  int ch = tid & 3;
  for (int ko = 0; ko < 8; ++ko) {
    __syncthreads();
    gload_lds16(Ab + (size_t)row * 256 + ko * 32 + ch * 8, As + tid * 8);
    gload_lds16(Ab + (size_t)(row + 64) * 256 + ko * 32 + ch * 8, As + 2048 + tid * 8);
    gload_lds16(Bb + (size_t)row * 256 + ko * 32 + ch * 8, Bs + tid * 8);
    gload_lds16(Bb + (size_t)(row + 64) * 256 + ko * 32 + ch * 8, Bs + 2048 + tid * 8);
    __syncthreads();
    bf16x8 af[4], bfr[4];
#pragma unroll
    for (int mt = 0; mt < 4; ++mt)
      af[mt] = *reinterpret_cast<const bf16x8*>(As + (wm * 64 + mt * 16 + (l & 15)) * 32 + (l >> 4) * 8);
#pragma unroll
    for (int nt = 0; nt < 4; ++nt)
      bfr[nt] = *reinterpret_cast<const bf16x8*>(Bs + (wn * 64 + nt * 16 + (l & 15)) * 32 + (l >> 4) * 8);
#pragma unroll
    for (int mt = 0; mt < 4; ++mt)
#pragma unroll
      for (int nt = 0; nt < 4; ++nt)
        acc[mt][nt] = __builtin_amdgcn_mfma_f32_16x16x32_bf16(af[mt], bfr[nt], acc[mt][nt], 0, 0, 0);
  }
#pragma unroll
  for (int mt = 0; mt < 4; ++mt) {
    int tm = bm * 8 + wm * 4 + mt;
#pragma unroll
    for (int nt = 0; nt < 4; ++nt) {
      int tn = bn * 8 + wn * 4 + nt;
      float bv = bias[tn * 16 + (l & 15)];
      u16x4 pk;
#pragma unroll
      for (int r = 0; r < 4; ++r) pk[r] = f2bf(acc[mt][nt][r] + bv);
      *reinterpret_cast<u16x4*>(xWp + ((size_t)(tm * 64 + tn) * 256 + l * 4)) = pk;
    }
  }
}

// ---------- phase 2: recurrence, CU-local, AGPR-pinned weights ----------
// 128 wgs x 512 threads. wg owns 2 batch rows (A rows replicated x8).
// Wave wid owns hidden units wid*32..+31, all 4 gates: Wh i8 slice pinned in
// 128 AGPRs per lane via inline-asm MFMA "a" constraints (no spill possible).
// 1 LSTM cell per lane -> 5 exp + 5 rcp per lane per step.
// Step body macro-expanded with compile-time CUR: no dynamic register-array
// indexing anywhere (anti-scratch). One lgkm-only raw barrier per step.
__global__ __launch_bounds__(512, 2) void lstm_rec(const signed char* __restrict__ Whq,
                                                   const float* __restrict__ wscale,
                                                   const u16* __restrict__ xWp,
                                                   float* __restrict__ out) {
  __shared__ __align__(16) signed char hb[2][576];   // 2 x (2 rows x 288B)
  int p = blockIdx.x;            // 0..127
  int xcd = p & 7, q8 = (p >> 3) & 7, tsel = p >> 6;
  int G = xcd * 2 + tsel;        // 16-row tile id; 8 co-XCD sharers
  int tid = threadIdx.x;
  int wid = tid >> 6, l = tid & 63;
  int c = l & 15, q = (l >> 4) & 3;
  int tt = q >> 1, rsel = q & 1;

  for (int i = tid; i < 288; i += 512) ((int*)hb)[i] = 0;

  // Wh i8 fragments: [gate][tt-tile][kstep] -> forced into AGPRs by asm "a" use
  i32x4 bw[4][2][4];
#pragma unroll
  for (int g = 0; g < 4; ++g)
#pragma unroll
    for (int ttl = 0; ttl < 2; ++ttl) {
      int col = g * 256 + wid * 32 + ttl * 16 + c;
#pragma unroll
      for (int ks = 0; ks < 4; ++ks)
        bw[g][ttl][ks] = *reinterpret_cast<const i32x4*>(Whq + (size_t)col * 256 + ks * 64 + q * 16);
    }
  float sc8[4];
#pragma unroll
  for (int g = 0; g < 4; ++g) sc8[g] = wscale[g * 256 + wid * 32 + tt * 16 + c];

  // xW: tile tm = t*16 + G; this wg's rows are regs {2*(q8&1), +1} of quad q8>>1
  const char* xbase = (const char*)xWp + (size_t)G * 32768;
  int xoff[4];
#pragma unroll
  for (int g = 0; g < 4; ++g) {
    int tn = g * 16 + wid * 2 + tt;
    xoff[g] = tn * 512 + (((q8 >> 1) * 16 + c) * 8) + (q8 & 1) * 4;
  }
  unsigned xw0[4], xw1[4];
#pragma unroll
  for (int g = 0; g < 4; ++g) xw0[g] = *(const unsigned*)(xbase + xoff[g]);   // t=0
  xbase += 524288;   // -> t=1

  i32x4 zacc = (i32x4){0, 0, 0, 0};
  float cs = 0.f, hh = 0.f;
  __syncthreads();

#define STEP(CUR, XW_CUR, XW_NXT)                                               \
  {                                                                             \
    _Pragma("unroll")                                                           \
    for (int g = 0; g < 4; ++g) XW_NXT[g] = *(const unsigned*)(xbase + xoff[g]);\
    const signed char* hr = hb[CUR ^ 1];                                        \
    i32x4 acc[4][2];                                                            \
    {                                                                           \
      i32x4 a0 = *(const i32x4*)(hr + (c & 1) * 288 + q * 16);                  \
      _Pragma("unroll")                                                         \
      for (int g = 0; g < 4; ++g) {                                             \
        __asm__("v_mfma_i32_16x16x64_i8 %0, %1, %2, %3"                         \
                : "=&v"(acc[g][0]) : "v"(a0), "a"(bw[g][0][0]), "v"(zacc));     \
        __asm__("v_mfma_i32_16x16x64_i8 %0, %1, %2, %3"                         \
                : "=&v"(acc[g][1]) : "v"(a0), "a"(bw[g][1][0]), "v"(zacc));     \
      }                                                                         \
    }                                                                           \
    _Pragma("unroll")                                                           \
    for (int ks = 1; ks < 4; ++ks) {                                            \
      i32x4 a = *(const i32x4*)(hr + (c & 1) * 288 + ks * 64 + q * 16);         \
      _Pragma("unroll")                                                         \
      for (int g = 0; g < 4; ++g) {                                             \
        __asm__("v_mfma_i32_16x16x64_i8 %0, %1, %2, %0"                         \
                : "+v"(acc[g][0]) : "v"(a), "a"(bw[g][0][ks]));                 \
        __asm__("v_mfma_i32_16x16x64_i8 %0, %1, %2, %0"                         \
                : "+v"(acc[g][1]) : "v"(a), "a"(bw[g][1][ks]));                 \
      }                                                                         \
    }                                                                           \
    __asm__ volatile("s_nop 7\n\ts_nop 7\n\ts_nop 7");  /* MFMA->VALU hazard */ \
    float a4[4];                                                                \
    _Pragma("unroll")                                                           \
    for (int g = 0; g < 4; ++g) {                                               \
      int e = tt ? (rsel ? acc[g][1][1] : acc[g][1][0])                         \
                 : (rsel ? acc[g][0][1] : acc[g][0][0]);                        \
      unsigned d = XW_CUR[g];                                                   \
      float xv = rsel ? bfhi(d) : bflo(d);                                      \
      a4[g] = (float)e * sc8[g] + xv;                                           \
    }                                                                           \
    float gi = fsig(a4[0]);                                                     \
    float gf = fsig(a4[1]);                                                     \
    float gg = ftanh(a4[2]);                                                    \
    float go = fsig(a4[3]);                                                     \
    cs = gf * cs + gi * gg;                                                     \
    hh = go * ftanh(cs);                                                        \
    int hq = (int)rintf(hh * 127.f);                                            \
    hb[CUR][rsel * 288 + wid * 32 + tt * 16 + c] = (signed char)hq;             \
    xbase += 524288;                                                            \
    __builtin_amdgcn_s_waitcnt(0xC07F);  /* lgkmcnt(0) only, vmcnt in flight */ \
    __builtin_amdgcn_s_barrier();                                               \
  }

  for (int t = 0; t < TT; t += 2) {
    STEP(0, xw0, xw1)
    STEP(1, xw1, xw0)
  }
#undef STEP

  {
    int n = G * 16 + q8 * 2 + rsel;
    int hu = wid * 32 + tt * 16 + c;
    out[(size_t)n * 256 + hu] = hh;
    out[65536 + (size_t)n * 256 + hu] = cs;
  }
}

// ---------- launch ----------
extern "C" void kernel_launch(void* const* d_in, const int* in_sizes, int n_in,
                              void* d_out, int out_size, void* d_ws, size_t ws_size,
                              hipStream_t stream) {
  const float* x   = (const float*)d_in[0];
  const float* wii = (const float*)d_in[1];
  const float* whi = (const float*)d_in[2];
  const float* wif = (const float*)d_in[3];
  const float* whf = (const float*)d_in[4];
  const float* wig = (const float*)d_in[5];
  const float* whg = (const float*)d_in[6];
  const float* wio = (const float*)d_in[7];
  const float* who = (const float*)d_in[8];
  const float* bii = (const float*)d_in[9];
  const float* bhi = (const float*)d_in[10];
  const float* bif = (const float*)d_in[11];
  const float* bhf = (const float*)d_in[12];
  const float* big_ = (const float*)d_in[13];
  const float* bhg = (const float*)d_in[14];
  const float* bio = (const float*)d_in[15];
  const float* bho = (const float*)d_in[16];

  char* ws = (char*)d_ws;
  u16*   xb     = (u16*)(ws);                         // 67,108,864 B
  u16*   Wxb    = (u16*)(ws + 67108864);              //    524,288 B
  signed char* Whq = (signed char*)(ws + 67633152);   //    262,144 B
  float* wscale = (float*)(ws + 67895296);            //      4,096 B
  float* bsum   = (float*)(ws + 67899392);            //      4,096 B
  u16*   xWp    = (u16*)(ws + 67903488);              // 268,435,456 B + 576 KB prefetch pad
  float* out = (float*)d_out;

  prep_x<<<32768, 256, 0, stream>>>(x, xb);
  prep_w<<<2049, 256, 0, stream>>>(wii, whi, wif, whf, wig, whg, wio, who,
                                   bii, bhi, bif, bhf, big_, bhg, bio, bho,
                                   Wxb, Whq, wscale, bsum);
  gemm_xw<<<8192, 256, 0, stream>>>(xb, Wxb, bsum, xWp);
  lstm_rec<<<128, 512, 0, stream>>>(Whq, wscale, xWp, out);
}